// Round 16
// baseline (182.495 us; speedup 1.0000x reference)
//
#include <hip/hip_runtime.h>
#include <math.h>

#define NB 2048
#define NV 110
#define NH1 5
#define NF1 24
#define NH2 3
#define NF2 3
#define C1 (NH1*NF1)   // 120
#define LALPHA 0.2f

constexpr int NN = NV*NV;          // 12100
constexpr int T1 = 1024;           // 16 waves/block, 2 blocks/CU -> 32 waves/CU
constexpr int KP = 136;            // padded K stride (halves)
constexpr int W1ROWS = 144;        // 120 feat cols + pad + 10 logit cols + pad

typedef _Float16 f16;
typedef f16  f16x8 __attribute__((ext_vector_type(8)));
typedef f16  f16x4 __attribute__((ext_vector_type(4)));
typedef __fp16 h16x2 __attribute__((ext_vector_type(2)));
typedef float f32x4 __attribute__((ext_vector_type(4)));

__device__ __forceinline__ f32x4 mfma16(f16x8 a, f16x8 b, f32x4 c) {
  return __builtin_amdgcn_mfma_f32_16x16x32_f16(a, b, c, 0, 0, 0);
}
__device__ __forceinline__ float lrelu(float x){ return x > 0.f ? x : LALPHA*x; }
__device__ __forceinline__ float frcp(float x){ return __builtin_amdgcn_rcpf(x); }
__device__ __forceinline__ float sigm(float x){ return frcp(1.f+__expf(-x)); }
// exp(v-4) as a single fma + hw exp2
__device__ __forceinline__ float expm4(float v){
  return __builtin_amdgcn_exp2f(fmaf(v, 1.442695041f, -5.770780163f));
}
__device__ __forceinline__ float wmax(float v){
  #pragma unroll
  for (int d=32; d; d>>=1) v = fmaxf(v, __shfl_xor(v,d));
  return v;
}
__device__ __forceinline__ float wsum(float v){
  #pragma unroll
  for (int d=32; d; d>>=1) v += __shfl_xor(v,d);
  return v;
}
__device__ __forceinline__ f32x4 ld4u(const float* p){
  f32x4 v; __builtin_memcpy(&v, p, 16); return v;
}

// ---- Kernel 0: precompute sigmoid(M), augmented W1^T, augmented W2^T, fc2^T ----
// W1tg rows: 0..119 = W1^T cat; 128+h = es-col head h; 133+h = en-col; rest 0
// W2tg rows: 0..8 = W2^T cat; 9+g = es2-col; 12+g = en2-col; 15 = 0
// fc2tg rows j=0..111: fc2tg[j][k] = fc2[k][j] (f16, zero-padded)
__global__ void precomp_kernel(const float* __restrict__ M, const float* __restrict__ W1,
                               const float* __restrict__ as1, const float* __restrict__ an1,
                               const float* __restrict__ W2, const float* __restrict__ as2,
                               const float* __restrict__ an2, const float* __restrict__ fc2w,
                               float* __restrict__ Msig, f16* __restrict__ W1tg,
                               f16* __restrict__ W2tg, f16* __restrict__ fc2tg) {
  const int i = blockIdx.x*256 + threadIdx.x;
  if (i < NN) {
    Msig[i] = sigm(M[i]);
  } else if (i < NN + W1ROWS*KP) {
    const int j = i - NN, f = j/KP, k = j%KP;
    float v = 0.f;
    if (k < NV) {
      if (f < C1) {
        v = W1[(f/NF1)*(NV*NF1) + k*NF1 + (f%NF1)];
      } else if (f >= 128 && f < 133) {
        const int h = f - 128;
        for (int ff = 0; ff < NF1; ++ff)
          v += W1[h*(NV*NF1) + k*NF1 + ff] * as1[h*NF1 + ff];
      } else if (f >= 133 && f < 138) {
        const int h = f - 133;
        for (int ff = 0; ff < NF1; ++ff)
          v += W1[h*(NV*NF1) + k*NF1 + ff] * an1[h*NF1 + ff];
      }
    }
    W1tg[f*KP + k] = (f16)v;
  } else if (i < NN + W1ROWS*KP + 16*KP) {
    const int j = i - NN - W1ROWS*KP, r = j/KP, k = j%KP;
    float v = 0.f;
    if (k < C1) {
      if (r < 9) {
        v = W2[(r/NF2)*(C1*NF2) + k*NF2 + (r%NF2)];
      } else if (r < 12) {
        const int g = r - 9;
        for (int f2 = 0; f2 < NF2; ++f2)
          v += W2[g*(C1*NF2) + k*NF2 + f2] * as2[g*NF2 + f2];
      } else if (r < 15) {
        const int g = r - 12;
        for (int f2 = 0; f2 < NF2; ++f2)
          v += W2[g*(C1*NF2) + k*NF2 + f2] * an2[g*NF2 + f2];
      }
    }
    W2tg[r*KP + k] = (f16)v;
  } else if (i < NN + W1ROWS*KP + 16*KP + 112*KP) {
    const int j = i - NN - W1ROWS*KP - 16*KP, col = j/KP, k = j%KP;
    float v = 0.f;
    if (col < NV && k < NV) v = fc2w[k*NV + col];
    fc2tg[col*KP + k] = (f16)v;
  }
}

// ---- fully fused GAT: 16 waves/block, work split (half = wv>>3, wq = wv&7) ----
__global__ __launch_bounds__(T1, 8) void gat_fused(
  const float* __restrict__ X, const float* __restrict__ A,
  const float* __restrict__ Msig, const f16* __restrict__ W1tg,
  const float* __restrict__ b1,  const f16* __restrict__ W2tg,
  const float* __restrict__ b2,  const float* __restrict__ fc1w,
  const f16* __restrict__ fc2tg, float* __restrict__ out)
{
  // LDS = 80,896 B (x2 blocks = 161,792 <= 163,840)
  __shared__ __attribute__((aligned(16))) f16 sXm [112*KP]; // Xm, then h1[n][c]
  __shared__ __attribute__((aligned(16))) f16 sFt [128*KP]; // feats^T [f][m]
  __shared__ __attribute__((aligned(16))) f16 sF2t[16*KP];  // feats2^T
  __shared__ __attribute__((aligned(16))) float sES [NH1*112]; // L1 es / sT,sS alias
  __shared__ __attribute__((aligned(16))) float sEN [NH1*128]; // L1 en
  __shared__ __attribute__((aligned(16))) float sES2[NH2*112]; // L2 es
  __shared__ __attribute__((aligned(16))) float sEN2[NH2*128]; // L2 en
  __shared__ unsigned long long sAM[2*112];
  __shared__ __attribute__((aligned(16))) float sHP[112*4];    // L2 g2 partials

  const int b = blockIdx.x, tid = threadIdx.x;
  const int wv = tid >> 6, lane = tid & 63;
  const int wq = wv & 7, half = wv >> 3;
  const int lr = lane & 15, lh = lane >> 4;
  const float* __restrict__ Xb = X + (size_t)b*NN;
  const float* __restrict__ Ab = A + (size_t)b*NN;

  float* const sT = sES;          // aliases, used only in the final phase
  float* const sS = sES + 128;

  // --- pad-only zero-init (disjoint from staged regions) ---
  for (int n = tid; n < 110; n += T1) {       // sXm rows<110: cols 110..135
    *(unsigned*)&sXm[n*KP + 110] = 0u;
    *(uint4*)&sXm[n*KP + 112] = uint4{0,0,0,0};
    *(uint4*)&sXm[n*KP + 120] = uint4{0,0,0,0};
    *(uint4*)&sXm[n*KP + 128] = uint4{0,0,0,0};
  }
  for (int i = tid; i < 2*KP/8; i += T1)      // sXm rows 110,111 full
    ((uint4*)&sXm[110*KP])[i] = uint4{0,0,0,0};
  for (int n = tid; n < 128; n += T1) {       // sFt: cols 112..135 per row
    *(uint4*)&sFt[n*KP + 112] = uint4{0,0,0,0};
    *(uint4*)&sFt[n*KP + 120] = uint4{0,0,0,0};
    *(uint4*)&sFt[n*KP + 128] = uint4{0,0,0,0};
  }
  for (int i = tid; i < (16*KP)/8; i += T1)   // sF2t entirely (row 15 stays 0)
    ((uint4*)sF2t)[i] = uint4{0,0,0,0};
  if (tid < 4) sAM[220 + tid] = 0ull;         // mask pad rows 110,111

  // --- stage Xm = X * Msig (float4 loads, pkrtz pack), adjacency ballot ---
  for (int t = tid; t < NV*28; t += T1) {
    const int n = t/28, c = t%28, k = 4*c;
    if (c < 27) {
      f32x4 x = ld4u(Xb + n*NV + k);
      f32x4 m = ld4u(Msig + n*NV + k);
      union { f16x4 v4; h16x2 h2[2]; } u;
      u.h2[0] = __builtin_amdgcn_cvt_pkrtz(x[0]*m[0], x[1]*m[1]);
      u.h2[1] = __builtin_amdgcn_cvt_pkrtz(x[2]*m[2], x[3]*m[3]);
      *(f16x4*)&sXm[n*KP + k] = u.v4;
    } else {
      sXm[n*KP + 108] = (f16)(Xb[n*NV+108]*Msig[n*NV+108]);
      sXm[n*KP + 109] = (f16)(Xb[n*NV+109]*Msig[n*NV+109]);
    }
  }
  #pragma unroll
  for (int i = 0; i < 7; ++i) {
    const int n = wv + 16*i;                      // wave-uniform
    if (n < NV) {
      unsigned long long m0 = __ballot(Ab[n*NV + lane] > 0.f);
      const int mm = 64 + lane;
      unsigned long long m1 = __ballot((mm < NV) && (Ab[n*NV + mm] > 0.f));
      if (lane == 0) { sAM[2*n] = m0; sAM[2*n+1] = m1; }
    }
  }
  // W1 B-fragments straight from global (L2-resident, zero-padded)
  f16x8 bW[4], bL[4];
  #pragma unroll
  for (int k = 0; k < 4; ++k)
    bW[k] = *(const f16x8*)&W1tg[(wq*16 + lr)*KP + k*32 + lh*8];
  if (half && wq < 7) {
    #pragma unroll
    for (int k = 0; k < 4; ++k)
      bL[k] = *(const f16x8*)&W1tg[(128 + lr)*KP + k*32 + lh*8];
  }
  __syncthreads();   // (1) Xm/masks staged

  // --- GEMM1: f-tile wq; half0 m0..3, half1 m4..6 + logit m-tile wq ---
  {
    const int mlo = half ? 4 : 0, mhi = half ? 7 : 4;
    for (int m = mlo; m < mhi; ++m) {
      f32x4 acc = {0.f,0.f,0.f,0.f};
      #pragma unroll
      for (int k = 0; k < 4; ++k) {
        f16x8 af = *(const f16x8*)&sXm[(m*16 + lr)*KP + k*32 + lh*8];
        acc = mfma16(af, bW[k], acc);
      }
      f16x4 v;
      #pragma unroll
      for (int r = 0; r < 4; ++r) v[r] = (f16)acc[r];
      *(f16x4*)&sFt[(wq*16 + lr)*KP + m*16 + lh*4] = v;   // sFt[f][m]
    }
    if (half && wq < 7) {     // logit m-tile m==wq
      f32x4 acc = {0.f,0.f,0.f,0.f};
      #pragma unroll
      for (int k = 0; k < 4; ++k) {
        f16x8 af = *(const f16x8*)&sXm[(wq*16 + lr)*KP + k*32 + lh*8];
        acc = mfma16(af, bL[k], acc);
      }
      const int mg0 = wq*16 + lh*4;
      if (lr < 5)       *(f32x4*)&sES[lr*112 + mg0] = acc;
      else if (lr < 10) *(f32x4*)&sEN[(lr-5)*128 + mg0] = acc;
    }
  }
  __syncthreads();   // (2) feats^T + L1 logits visible

  // ============ L1 passes: m-tile wq; half0 heads 0-2, half1 heads 3-4 ====
  const int row  = wq*16 + lr;
  const int arow = (row < 112) ? row : 0;     // clamp (wq==7 rows unused)
  const unsigned long long am0 = sAM[2*arow], am1 = sAM[2*arow+1];
  const float bvt0 = (lr < NF1) ? b1[lr] : 0.f;
  const float bvt1 = (16 + lr < NF1) ? b1[16 + lr] : 0.f;
  const int np = half ? 2 : 3, pbase = half ? 3 : 0;

  f16 h1r[3][2][4];
  f16x8 pa[4];
  if (wq < 7) {
    #pragma unroll
    for (int pi = 0; pi < 3; ++pi) {
      if (pi < np) {
        const int p = pbase + pi;
        const float es = sES[p*112 + row];
        float psum = 0.f;
        #pragma unroll
        for (int k = 0; k < 4; ++k) {
          const int cb = k*32 + lh*8;
          const f32x4 enA = *(const f32x4*)&sEN[p*128 + cb];
          const f32x4 enB = *(const f32x4*)&sEN[p*128 + cb + 4];
          const unsigned bits = (unsigned)(((cb & 64) ? am1 : am0) >> (cb & 63)) & 0xFFu;
          float e[8];
          #pragma unroll
          for (int j = 0; j < 8; ++j) {
            float v = es + ((j < 4) ? enA[j] : enB[j-4]);
            v = fmaxf(v, LALPHA*v);                 // leaky_relu
            v = (bits & (1u << j)) ? v : -1e30f;    // adjacency mask
            e[j] = expm4(v);                        // exp(v-4)
          }
          psum += ((e[0]+e[1]) + (e[2]+e[3])) + ((e[4]+e[5]) + (e[6]+e[7]));
          union { f16x8 v8; h16x2 h2[4]; } u;
          u.h2[0] = __builtin_amdgcn_cvt_pkrtz(e[0], e[1]);
          u.h2[1] = __builtin_amdgcn_cvt_pkrtz(e[2], e[3]);
          u.h2[2] = __builtin_amdgcn_cvt_pkrtz(e[4], e[5]);
          u.h2[3] = __builtin_amdgcn_cvt_pkrtz(e[6], e[7]);
          pa[k] = u.v8;
        }
        psum += __shfl_xor(psum, 16);     // row-sum across lh groups
        psum += __shfl_xor(psum, 32);
        f32x4 rs;
        #pragma unroll
        for (int r = 0; r < 4; ++r) rs[r] = __shfl(psum, lh*4 + r);
        #pragma unroll
        for (int nt2 = 0; nt2 < 2; ++nt2) {
          f32x4 acc = {0.f,0.f,0.f,0.f};
          #pragma unroll
          for (int k = 0; k < 4; ++k) {
            f16x8 bf = *(const f16x8*)&sFt[(p*NF1 + nt2*16 + lr)*KP + k*32 + lh*8];
            acc = mfma16(pa[k], bf, acc);
          }
          const float bv = nt2 ? bvt1 : bvt0;
          #pragma unroll
          for (int r = 0; r < 4; ++r)
            h1r[pi][nt2][r] = (f16)lrelu(acc[r]*frcp(rs[r]) + bv);
        }
      }
    }
    // --- dump h1 regs -> sXm rows of m-tile wq (disjoint cols per half) ---
    #pragma unroll
    for (int pi = 0; pi < 3; ++pi) {
      if (pi < np) {
        const int p = pbase + pi;
        #pragma unroll
        for (int nt2 = 0; nt2 < 2; ++nt2) {
          const int fl = nt2*16 + lr;
          if (fl < NF1) {
            #pragma unroll
            for (int r = 0; r < 4; ++r) {
              const int mg = wq*16 + lh*4 + r;
              if (mg < NV) sXm[mg*KP + p*NF1 + fl] = h1r[pi][nt2][r];
            }
          }
        }
      }
    }
  }
  __syncthreads();   // (2.5) h1 complete (both halves' columns)

  // --- feats2 = h1 @ W2aug : half0 wq<7; cols 0..8 feats2, 9..14 logits ---
  if (!half && wq < 7) {
    f32x4 acc = {0.f,0.f,0.f,0.f};
    #pragma unroll
    for (int k = 0; k < 4; ++k) {
      f16x8 af = *(const f16x8*)&sXm[(wq*16 + lr)*KP + k*32 + lh*8];
      f16x8 bf = *(const f16x8*)&W2tg[lr*KP + k*32 + lh*8];
      acc = mfma16(af, bf, acc);
    }
    const int mg0 = wq*16 + lh*4;
    if (lr < 9) {
      #pragma unroll
      for (int r = 0; r < 4; ++r) {
        const int mg = mg0 + r;
        if (mg < NV) sF2t[lr*KP + mg] = (f16)acc[r];
      }
    } else if (lr < 12) {
      *(f32x4*)&sES2[(lr-9)*112 + mg0] = acc;
    } else if (lr < 15) {
      *(f32x4*)&sEN2[(lr-12)*128 + mg0] = acc;
    }
  }
  __syncthreads();   // (3) feats2^T + L2 logits visible

  // ============ L2 passes: m-tile wq; half0 g{0,1}, half1 g{2} ============
  f32x4 a2A = {0.f,0.f,0.f,0.f};
  f32x4 a2B = {0.f,0.f,0.f,0.f};
  float psA = 0.f, psB = 0.f;
  const int ng = half ? 1 : 2, gbase = half ? 2 : 0;
  if (wv == 15 && lane < 18) sT[110 + lane] = 0.f;   // zero-pad sT (idle wave)
  if (wq < 7) {
    #pragma unroll
    for (int gi = 0; gi < 2; ++gi) {
      if (gi < ng) {
        const int g = gbase + gi;
        const float es = sES2[g*112 + row];
        float psum = 0.f;
        #pragma unroll
        for (int k = 0; k < 4; ++k) {
          const int cb = k*32 + lh*8;
          const f32x4 enA = *(const f32x4*)&sEN2[g*128 + cb];
          const f32x4 enB = *(const f32x4*)&sEN2[g*128 + cb + 4];
          const unsigned bits = (unsigned)(((cb & 64) ? am1 : am0) >> (cb & 63)) & 0xFFu;
          float e[8];
          #pragma unroll
          for (int j = 0; j < 8; ++j) {
            float v = es + ((j < 4) ? enA[j] : enB[j-4]);
            v = fmaxf(v, LALPHA*v);
            v = (bits & (1u << j)) ? v : -1e30f;
            e[j] = expm4(v);
          }
          psum += ((e[0]+e[1]) + (e[2]+e[3])) + ((e[4]+e[5]) + (e[6]+e[7]));
          union { f16x8 v8; h16x2 h2[4]; } u;
          u.h2[0] = __builtin_amdgcn_cvt_pkrtz(e[0], e[1]);
          u.h2[1] = __builtin_amdgcn_cvt_pkrtz(e[2], e[3]);
          u.h2[2] = __builtin_amdgcn_cvt_pkrtz(e[4], e[5]);
          u.h2[3] = __builtin_amdgcn_cvt_pkrtz(e[6], e[7]);
          pa[k] = u.v8;
        }
        psum += __shfl_xor(psum, 16);
        psum += __shfl_xor(psum, 32);
        if (gi == 0) psA = psum; else psB = psum;
        const int brow = (lr < NF2) ? (g*NF2 + lr) : 15;   // row 15 stays zero
        #pragma unroll
        for (int k = 0; k < 4; ++k) {
          f16x8 bf = *(const f16x8*)&sF2t[brow*KP + k*32 + lh*8];
          if (gi == 0) a2A = mfma16(pa[k], bf, a2A);
          else         a2B = mfma16(pa[k], bf, a2B);
        }
      }
    }
  }
  // half1 deposits its g2 partial (a2/rowsum) for the combine
  if (half && wq < 7) {
    #pragma unroll
    for (int r = 0; r < 4; ++r) {
      const int mg = wq*16 + lh*4 + r;
      const float rs2 = __shfl(psA, lh*4 + r);
      if (lr < NF2 && mg < NV) sHP[mg*4 + lr] = a2A[r]*frcp(rs2);
    }
  }
  __syncthreads();   // (3.5) g2 partials visible

  // --- t[n] = sigmoid( lrelu(mean_g + b2) . fc1 )  (half0 combines) ---
  if (!half && wq < 7) {
    const float fcv = (lr < NF2) ? fc1w[lr] : 0.f;
    const float b2v = (lr < NF2) ? b2[lr]  : 0.f;
    #pragma unroll
    for (int r = 0; r < 4; ++r) {
      const int mg = wq*16 + lh*4 + r;
      const float rs0 = __shfl(psA, lh*4 + r);
      const float rs1 = __shfl(psB, lh*4 + r);
      float hsum = a2A[r]*frcp(rs0) + a2B[r]*frcp(rs1);
      if (lr < NF2 && mg < NV) hsum += sHP[mg*4 + lr];
      float hv = (lr < NF2) ? lrelu(hsum*(1.f/NH2) + b2v)*fcv : 0.f;
      hv += __shfl_xor(hv, 1);
      hv += __shfl_xor(hv, 2);
      hv += __shfl_xor(hv, 4);
      hv += __shfl_xor(hv, 8);
      if (lr == 0 && mg < NV) sT[mg] = sigm(hv);
    }
  }
  __syncthreads();   // (4) sT complete (incl. zero pad)

  // --- s = t @ fc2 via MFMA; A-fragment built per-lane from sT ---
  if (!half && wq < 7) {
    f32x4 acc = {0.f,0.f,0.f,0.f};
    #pragma unroll
    for (int k = 0; k < 4; ++k) {
      const int cb = k*32 + lh*8;
      const f32x4 tA = *(const f32x4*)&sT[cb];
      const f32x4 tB = *(const f32x4*)&sT[cb + 4];
      union { f16x8 v8; h16x2 h2[4]; } u;
      u.h2[0] = __builtin_amdgcn_cvt_pkrtz(tA[0], tA[1]);
      u.h2[1] = __builtin_amdgcn_cvt_pkrtz(tA[2], tA[3]);
      u.h2[2] = __builtin_amdgcn_cvt_pkrtz(tB[0], tB[1]);
      u.h2[3] = __builtin_amdgcn_cvt_pkrtz(tB[2], tB[3]);
      f16x8 bf = *(const f16x8*)&fc2tg[(wq*16 + lr)*KP + k*32 + lh*8];
      acc = mfma16(u.v8, bf, acc);
    }
    const int col = wq*16 + lr;
    if (lh == 0 && col < NV) sS[col] = acc[0];
  }
  __syncthreads();   // (5)
  // --- out[b] = sum_m t[m]*softmax(s)[m] ---
  if (wv == 0) {
    const float s0 = sS[lane];
    const float s1 = (64+lane < NV) ? sS[64+lane] : -1e38f;
    const float mx = wmax(fmaxf(s0, s1));
    const float p0 = __expf(s0 - mx);
    const float p1 = (64+lane < NV) ? __expf(s1 - mx) : 0.f;
    const float sum = wsum(p0 + p1);
    float val = sT[lane]*p0 + ((64+lane < NV) ? sT[64+lane]*p1 : 0.f);
    val = wsum(val);
    if (lane == 0) out[b] = val*frcp(sum);
  }
}

extern "C" void kernel_launch(void* const* d_in, const int* in_sizes, int n_in,
                              void* d_out, int out_size, void* d_ws, size_t ws_size,
                              hipStream_t stream) {
  const float* X   = (const float*)d_in[0];
  const float* A   = (const float*)d_in[1];
  const float* M   = (const float*)d_in[2];
  const float* W1  = (const float*)d_in[3];
  const float* as1 = (const float*)d_in[4];
  const float* an1 = (const float*)d_in[5];
  const float* b1  = (const float*)d_in[6];
  const float* W2  = (const float*)d_in[7];
  const float* as2 = (const float*)d_in[8];
  const float* an2 = (const float*)d_in[9];
  const float* b2  = (const float*)d_in[10];
  const float* fc1 = (const float*)d_in[11];
  const float* fc2 = (const float*)d_in[12];
  float* out = (float*)d_out;

  // ws: Msig f32[12100] | W1tg f16[144*136] | W2tg f16[16*136] | fc2tg f16[112*136]
  float* Msig = (float*)d_ws;
  f16* W1tg  = (f16*)((char*)d_ws + 48400);
  f16* W2tg  = (f16*)((char*)d_ws + 48400 + W1ROWS*KP*2);
  f16* fc2tg = (f16*)((char*)d_ws + 48400 + W1ROWS*KP*2 + 16*KP*2);

  const int pre_items = NN + W1ROWS*KP + 16*KP + 112*KP;
  precomp_kernel<<<(pre_items + 255)/256, 256, 0, stream>>>(
      M, W1, as1, an1, W2, as2, an2, fc2, Msig, W1tg, W2tg, fc2tg);
  gat_fused<<<NB, T1, 0, stream>>>(X, A, Msig, W1tg, b1, W2tg,
                                   b2, fc1, fc2tg, out);
}

// Round 17
// 157.214 us; speedup vs baseline: 1.1608x; 1.1608x over previous
//
#include <hip/hip_runtime.h>
#include <math.h>

#define NB 2048
#define NV 110
#define NH1 5
#define NF1 24
#define NH2 3
#define NF2 3
#define C1 (NH1*NF1)   // 120
#define LALPHA 0.2f

constexpr int NN = NV*NV;          // 12100
constexpr int T1 = 768;            // 12 waves/block, 2 blocks/CU -> 24 waves/CU
constexpr int KP = 136;            // padded K stride (halves)
constexpr int W1ROWS = 144;        // 120 feat cols + pad + 10 logit cols + pad

typedef _Float16 f16;
typedef f16  f16x8 __attribute__((ext_vector_type(8)));
typedef f16  f16x4 __attribute__((ext_vector_type(4)));
typedef __fp16 h16x2 __attribute__((ext_vector_type(2)));
typedef float f32x4 __attribute__((ext_vector_type(4)));

__device__ __forceinline__ f32x4 mfma16(f16x8 a, f16x8 b, f32x4 c) {
  return __builtin_amdgcn_mfma_f32_16x16x32_f16(a, b, c, 0, 0, 0);
}
__device__ __forceinline__ float lrelu(float x){ return x > 0.f ? x : LALPHA*x; }
__device__ __forceinline__ float frcp(float x){ return __builtin_amdgcn_rcpf(x); }
__device__ __forceinline__ float sigm(float x){ return frcp(1.f+__expf(-x)); }
// exp(v-4) as a single fma + hw exp2
__device__ __forceinline__ float expm4(float v){
  return __builtin_amdgcn_exp2f(fmaf(v, 1.442695041f, -5.770780163f));
}
__device__ __forceinline__ float wmax(float v){
  #pragma unroll
  for (int d=32; d; d>>=1) v = fmaxf(v, __shfl_xor(v,d));
  return v;
}
__device__ __forceinline__ float wsum(float v){
  #pragma unroll
  for (int d=32; d; d>>=1) v += __shfl_xor(v,d);
  return v;
}
__device__ __forceinline__ f32x4 ld4u(const float* p){
  f32x4 v; __builtin_memcpy(&v, p, 16); return v;
}

// ---- Kernel 0: precompute sigmoid(M), augmented W1^T, augmented W2^T, fc2^T ----
// W1tg rows: 0..119 = W1^T cat; 128+h = es-col head h; 133+h = en-col; rest 0
// W2tg rows: 0..8 = W2^T cat; 9+g = es2-col; 12+g = en2-col; 15 = 0
// fc2tg rows j=0..111: fc2tg[j][k] = fc2[k][j] (f16, zero-padded)
__global__ void precomp_kernel(const float* __restrict__ M, const float* __restrict__ W1,
                               const float* __restrict__ as1, const float* __restrict__ an1,
                               const float* __restrict__ W2, const float* __restrict__ as2,
                               const float* __restrict__ an2, const float* __restrict__ fc2w,
                               float* __restrict__ Msig, f16* __restrict__ W1tg,
                               f16* __restrict__ W2tg, f16* __restrict__ fc2tg) {
  const int i = blockIdx.x*256 + threadIdx.x;
  if (i < NN) {
    Msig[i] = sigm(M[i]);
  } else if (i < NN + W1ROWS*KP) {
    const int j = i - NN, f = j/KP, k = j%KP;
    float v = 0.f;
    if (k < NV) {
      if (f < C1) {
        v = W1[(f/NF1)*(NV*NF1) + k*NF1 + (f%NF1)];
      } else if (f >= 128 && f < 133) {
        const int h = f - 128;
        for (int ff = 0; ff < NF1; ++ff)
          v += W1[h*(NV*NF1) + k*NF1 + ff] * as1[h*NF1 + ff];
      } else if (f >= 133 && f < 138) {
        const int h = f - 133;
        for (int ff = 0; ff < NF1; ++ff)
          v += W1[h*(NV*NF1) + k*NF1 + ff] * an1[h*NF1 + ff];
      }
    }
    W1tg[f*KP + k] = (f16)v;
  } else if (i < NN + W1ROWS*KP + 16*KP) {
    const int j = i - NN - W1ROWS*KP, r = j/KP, k = j%KP;
    float v = 0.f;
    if (k < C1) {
      if (r < 9) {
        v = W2[(r/NF2)*(C1*NF2) + k*NF2 + (r%NF2)];
      } else if (r < 12) {
        const int g = r - 9;
        for (int f2 = 0; f2 < NF2; ++f2)
          v += W2[g*(C1*NF2) + k*NF2 + f2] * as2[g*NF2 + f2];
      } else if (r < 15) {
        const int g = r - 12;
        for (int f2 = 0; f2 < NF2; ++f2)
          v += W2[g*(C1*NF2) + k*NF2 + f2] * an2[g*NF2 + f2];
      }
    }
    W2tg[r*KP + k] = (f16)v;
  } else if (i < NN + W1ROWS*KP + 16*KP + 112*KP) {
    const int j = i - NN - W1ROWS*KP - 16*KP, col = j/KP, k = j%KP;
    float v = 0.f;
    if (col < NV && k < NV) v = fc2w[k*NV + col];
    fc2tg[col*KP + k] = (f16)v;
  }
}

// ---- fully fused GAT: 12 waves/block, job-based distribution ----
__global__ __launch_bounds__(T1, 6) void gat_fused(
  const float* __restrict__ X, const float* __restrict__ A,
  const float* __restrict__ Msig, const f16* __restrict__ W1tg,
  const float* __restrict__ b1,  const f16* __restrict__ W2tg,
  const float* __restrict__ b2,  const float* __restrict__ fc1w,
  const f16* __restrict__ fc2tg, float* __restrict__ out)
{
  // LDS = 79,104 B (x2 blocks = 158,208 <= 163,840)
  __shared__ __attribute__((aligned(16))) f16 sXm [112*KP]; // Xm, then h1[n][c]
  __shared__ __attribute__((aligned(16))) f16 sFt [128*KP]; // feats^T / L2 partials
  __shared__ __attribute__((aligned(16))) f16 sF2t[16*KP];  // feats2^T
  __shared__ __attribute__((aligned(16))) float sES [NH1*112]; // L1 es / sT,sS alias
  __shared__ __attribute__((aligned(16))) float sEN [NH1*128]; // L1 en
  __shared__ __attribute__((aligned(16))) float sES2[NH2*112]; // L2 es
  __shared__ __attribute__((aligned(16))) float sEN2[NH2*128]; // L2 en
  __shared__ unsigned long long sAM[2*112];

  const int b = blockIdx.x, tid = threadIdx.x;
  const int wv = tid >> 6, lane = tid & 63;
  const int lr = lane & 15, lh = lane >> 4;
  const float* __restrict__ Xb = X + (size_t)b*NN;
  const float* __restrict__ Ab = A + (size_t)b*NN;

  float* const sT = sES;          // aliases, used only in the final phase
  float* const sS = sES + 128;
  float* const sHPf = (float*)sFt;   // L2 partials [g][n][f2] (sFt dead by then)

  // --- pad-only zero-init (disjoint from staged regions) ---
  for (int n = tid; n < 110; n += T1) {       // sXm rows<110: cols 110..135
    *(unsigned*)&sXm[n*KP + 110] = 0u;
    *(uint4*)&sXm[n*KP + 112] = uint4{0,0,0,0};
    *(uint4*)&sXm[n*KP + 120] = uint4{0,0,0,0};
    *(uint4*)&sXm[n*KP + 128] = uint4{0,0,0,0};
  }
  for (int i = tid; i < 2*KP/8; i += T1)      // sXm rows 110,111 full
    ((uint4*)&sXm[110*KP])[i] = uint4{0,0,0,0};
  for (int n = tid; n < 128; n += T1) {       // sFt: cols 112..135 per row
    *(uint4*)&sFt[n*KP + 112] = uint4{0,0,0,0};
    *(uint4*)&sFt[n*KP + 120] = uint4{0,0,0,0};
    *(uint4*)&sFt[n*KP + 128] = uint4{0,0,0,0};
  }
  for (int i = tid; i < (16*KP)/8; i += T1)   // sF2t entirely (row 15 stays 0)
    ((uint4*)sF2t)[i] = uint4{0,0,0,0};
  if (tid < 4) sAM[220 + tid] = 0ull;         // mask pad rows 110,111

  // --- stage Xm = X * Msig (float4 loads, pkrtz pack), adjacency ballot ---
  for (int t = tid; t < NV*28; t += T1) {
    const int n = t/28, c = t%28, k = 4*c;
    if (c < 27) {
      f32x4 x = ld4u(Xb + n*NV + k);
      f32x4 m = ld4u(Msig + n*NV + k);
      union { f16x4 v4; h16x2 h2[2]; } u;
      u.h2[0] = __builtin_amdgcn_cvt_pkrtz(x[0]*m[0], x[1]*m[1]);
      u.h2[1] = __builtin_amdgcn_cvt_pkrtz(x[2]*m[2], x[3]*m[3]);
      *(f16x4*)&sXm[n*KP + k] = u.v4;
    } else {
      sXm[n*KP + 108] = (f16)(Xb[n*NV+108]*Msig[n*NV+108]);
      sXm[n*KP + 109] = (f16)(Xb[n*NV+109]*Msig[n*NV+109]);
    }
  }
  #pragma unroll
  for (int i = 0; i < 10; ++i) {
    const int n = wv + 12*i;                      // wave-uniform
    if (n < NV) {
      unsigned long long m0 = __ballot(Ab[n*NV + lane] > 0.f);
      const int mm = 64 + lane;
      unsigned long long m1 = __ballot((mm < NV) && (Ab[n*NV + mm] > 0.f));
      if (lane == 0) { sAM[2*n] = m0; sAM[2*n+1] = m1; }
    }
  }
  __syncthreads();   // (1) Xm/masks staged

  // --- GEMM1: 63 jobs = 8 f-tiles x 7 m-tiles + 7 logit m-tiles ---
  #pragma unroll 1
  for (int j = wv; j < 63; j += 12) {
    const int ft = j/7, m = j%7;
    const int brow = (ft < 8) ? (ft*16 + lr) : (128 + lr);
    f16x8 bf[4];
    #pragma unroll
    for (int k = 0; k < 4; ++k)
      bf[k] = *(const f16x8*)&W1tg[brow*KP + k*32 + lh*8];
    f32x4 acc = {0.f,0.f,0.f,0.f};
    #pragma unroll
    for (int k = 0; k < 4; ++k) {
      f16x8 af = *(const f16x8*)&sXm[(m*16 + lr)*KP + k*32 + lh*8];
      acc = mfma16(af, bf[k], acc);
    }
    if (ft < 8) {
      f16x4 v;
      #pragma unroll
      for (int r = 0; r < 4; ++r) v[r] = (f16)acc[r];
      *(f16x4*)&sFt[(ft*16 + lr)*KP + m*16 + lh*4] = v;   // sFt[f][m]
    } else {
      const int mg0 = m*16 + lh*4;
      if (lr < 5)       *(f32x4*)&sES[lr*112 + mg0] = acc;
      else if (lr < 10) *(f32x4*)&sEN[(lr-5)*128 + mg0] = acc;
    }
  }
  __syncthreads();   // (2) feats^T + L1 logits visible

  const float bvt0 = (lr < NF1) ? b1[lr] : 0.f;
  const float bvt1 = (16 + lr < NF1) ? b1[16 + lr] : 0.f;

  // ============ L1: 35 jobs = (head p, m-tile m); h1 written per job =======
  f16x8 pa[4];
  #pragma unroll 1
  for (int j = wv; j < 35; j += 12) {
    const int p = j/7, m = j%7;
    const int row = m*16 + lr;
    const unsigned long long am0 = sAM[2*row], am1 = sAM[2*row+1];
    const float es = sES[p*112 + row];
    float psum = 0.f;
    #pragma unroll
    for (int k = 0; k < 4; ++k) {
      const int cb = k*32 + lh*8;
      const f32x4 enA = *(const f32x4*)&sEN[p*128 + cb];
      const f32x4 enB = *(const f32x4*)&sEN[p*128 + cb + 4];
      const unsigned bits = (unsigned)(((cb & 64) ? am1 : am0) >> (cb & 63)) & 0xFFu;
      float e[8];
      #pragma unroll
      for (int jj = 0; jj < 8; ++jj) {
        float v = es + ((jj < 4) ? enA[jj] : enB[jj-4]);
        v = fmaxf(v, LALPHA*v);                 // leaky_relu
        v = (bits & (1u << jj)) ? v : -1e30f;   // adjacency mask
        e[jj] = expm4(v);                       // exp(v-4)
      }
      psum += ((e[0]+e[1]) + (e[2]+e[3])) + ((e[4]+e[5]) + (e[6]+e[7]));
      union { f16x8 v8; h16x2 h2[4]; } u;
      u.h2[0] = __builtin_amdgcn_cvt_pkrtz(e[0], e[1]);
      u.h2[1] = __builtin_amdgcn_cvt_pkrtz(e[2], e[3]);
      u.h2[2] = __builtin_amdgcn_cvt_pkrtz(e[4], e[5]);
      u.h2[3] = __builtin_amdgcn_cvt_pkrtz(e[6], e[7]);
      pa[k] = u.v8;
    }
    psum += __shfl_xor(psum, 16);     // row-sum across lh groups
    psum += __shfl_xor(psum, 32);
    f32x4 rs;
    #pragma unroll
    for (int r = 0; r < 4; ++r) rs[r] = __shfl(psum, lh*4 + r);
    // GEMM2 (both f-tiles); h1 epilogue written straight to LDS (Xm dead)
    #pragma unroll
    for (int nt2 = 0; nt2 < 2; ++nt2) {
      f32x4 acc = {0.f,0.f,0.f,0.f};
      #pragma unroll
      for (int k = 0; k < 4; ++k) {
        f16x8 bf = *(const f16x8*)&sFt[(p*NF1 + nt2*16 + lr)*KP + k*32 + lh*8];
        acc = mfma16(pa[k], bf, acc);
      }
      const int fl = nt2*16 + lr;
      const float bv = nt2 ? bvt1 : bvt0;
      if (fl < NF1) {
        #pragma unroll
        for (int r = 0; r < 4; ++r) {
          const int mg = m*16 + lh*4 + r;
          if (mg < NV)
            sXm[mg*KP + p*NF1 + fl] = (f16)lrelu(acc[r]*frcp(rs[r]) + bv);
        }
      }
    }
  }
  __syncthreads();   // (2.5) h1 complete

  // --- feats2 = h1 @ W2aug : waves 0..6 (m-tile wv) ---
  if (wv < 7) {
    f32x4 acc = {0.f,0.f,0.f,0.f};
    #pragma unroll
    for (int k = 0; k < 4; ++k) {
      f16x8 af = *(const f16x8*)&sXm[(wv*16 + lr)*KP + k*32 + lh*8];
      f16x8 bf = *(const f16x8*)&W2tg[lr*KP + k*32 + lh*8];
      acc = mfma16(af, bf, acc);
    }
    const int mg0 = wv*16 + lh*4;
    if (lr < 9) {
      #pragma unroll
      for (int r = 0; r < 4; ++r) {
        const int mg = mg0 + r;
        if (mg < NV) sF2t[lr*KP + mg] = (f16)acc[r];
      }
    } else if (lr < 12) {
      *(f32x4*)&sES2[(lr-9)*112 + mg0] = acc;
    } else if (lr < 15) {
      *(f32x4*)&sEN2[(lr-12)*128 + mg0] = acc;
    }
  }
  __syncthreads();   // (3) feats2^T + L2 logits visible; sFt now dead

  // ============ L2: 21 jobs = (head g, m-tile m); partials into sHPf =======
  #pragma unroll 1
  for (int j = wv; j < 21; j += 12) {
    const int g = j/7, m = j%7;
    const int row = m*16 + lr;
    const unsigned long long am0 = sAM[2*row], am1 = sAM[2*row+1];
    const float es = sES2[g*112 + row];
    float psum = 0.f;
    #pragma unroll
    for (int k = 0; k < 4; ++k) {
      const int cb = k*32 + lh*8;
      const f32x4 enA = *(const f32x4*)&sEN2[g*128 + cb];
      const f32x4 enB = *(const f32x4*)&sEN2[g*128 + cb + 4];
      const unsigned bits = (unsigned)(((cb & 64) ? am1 : am0) >> (cb & 63)) & 0xFFu;
      float e[8];
      #pragma unroll
      for (int jj = 0; jj < 8; ++jj) {
        float v = es + ((jj < 4) ? enA[jj] : enB[jj-4]);
        v = fmaxf(v, LALPHA*v);
        v = (bits & (1u << jj)) ? v : -1e30f;
        e[jj] = expm4(v);
      }
      psum += ((e[0]+e[1]) + (e[2]+e[3])) + ((e[4]+e[5]) + (e[6]+e[7]));
      union { f16x8 v8; h16x2 h2[4]; } u;
      u.h2[0] = __builtin_amdgcn_cvt_pkrtz(e[0], e[1]);
      u.h2[1] = __builtin_amdgcn_cvt_pkrtz(e[2], e[3]);
      u.h2[2] = __builtin_amdgcn_cvt_pkrtz(e[4], e[5]);
      u.h2[3] = __builtin_amdgcn_cvt_pkrtz(e[6], e[7]);
      pa[k] = u.v8;
    }
    psum += __shfl_xor(psum, 16);
    psum += __shfl_xor(psum, 32);
    f32x4 rs;
    #pragma unroll
    for (int r = 0; r < 4; ++r) rs[r] = __shfl(psum, lh*4 + r);
    const int brow = (lr < NF2) ? (g*NF2 + lr) : 15;   // row 15 stays zero
    f32x4 acc = {0.f,0.f,0.f,0.f};
    #pragma unroll
    for (int k = 0; k < 4; ++k) {
      f16x8 bf = *(const f16x8*)&sF2t[brow*KP + k*32 + lh*8];
      acc = mfma16(pa[k], bf, acc);
    }
    #pragma unroll
    for (int r = 0; r < 4; ++r) {
      const int mg = m*16 + lh*4 + r;
      if (lr < NF2 && mg < NV)
        sHPf[g*448 + mg*4 + lr] = acc[r]*frcp(rs[r]);
    }
  }
  if (wv == 11 && lane < 18) sT[110 + lane] = 0.f;   // zero-pad sT (spare wave)
  __syncthreads();   // (3.5) L2 partials visible

  // --- t[n] = sigmoid( lrelu(mean_g + b2) . fc1 )  (waves 0..6, m-tile wv) --
  if (wv < 7) {
    const float fcv = (lr < NF2) ? fc1w[lr] : 0.f;
    const float b2v = (lr < NF2) ? b2[lr]  : 0.f;
    #pragma unroll
    for (int r = 0; r < 4; ++r) {
      const int mg = wv*16 + lh*4 + r;
      float hsum = 0.f;
      if (lr < NF2 && mg < NV)
        hsum = sHPf[mg*4 + lr] + sHPf[448 + mg*4 + lr] + sHPf[896 + mg*4 + lr];
      float hv = (lr < NF2) ? lrelu(hsum*(1.f/NH2) + b2v)*fcv : 0.f;
      hv += __shfl_xor(hv, 1);
      hv += __shfl_xor(hv, 2);
      hv += __shfl_xor(hv, 4);
      hv += __shfl_xor(hv, 8);
      if (lr == 0 && mg < NV) sT[mg] = sigm(hv);
    }
  }
  __syncthreads();   // (4) sT complete (incl. zero pad)

  // --- s = t @ fc2 via MFMA; A-fragment built per-lane from sT ---
  if (wv < 7) {
    f32x4 acc = {0.f,0.f,0.f,0.f};
    #pragma unroll
    for (int k = 0; k < 4; ++k) {
      const int cb = k*32 + lh*8;
      const f32x4 tA = *(const f32x4*)&sT[cb];
      const f32x4 tB = *(const f32x4*)&sT[cb + 4];
      union { f16x8 v8; h16x2 h2[4]; } u;
      u.h2[0] = __builtin_amdgcn_cvt_pkrtz(tA[0], tA[1]);
      u.h2[1] = __builtin_amdgcn_cvt_pkrtz(tA[2], tA[3]);
      u.h2[2] = __builtin_amdgcn_cvt_pkrtz(tB[0], tB[1]);
      u.h2[3] = __builtin_amdgcn_cvt_pkrtz(tB[2], tB[3]);
      f16x8 bf = *(const f16x8*)&fc2tg[(wv*16 + lr)*KP + k*32 + lh*8];
      acc = mfma16(u.v8, bf, acc);
    }
    const int col = wv*16 + lr;
    if (lh == 0 && col < NV) sS[col] = acc[0];
  }
  __syncthreads();   // (5)
  // --- out[b] = sum_m t[m]*softmax(s)[m] ---
  if (wv == 0) {
    const float s0 = sS[lane];
    const float s1 = (64+lane < NV) ? sS[64+lane] : -1e38f;
    const float mx = wmax(fmaxf(s0, s1));
    const float p0 = __expf(s0 - mx);
    const float p1 = (64+lane < NV) ? __expf(s1 - mx) : 0.f;
    const float sum = wsum(p0 + p1);
    float val = sT[lane]*p0 + ((64+lane < NV) ? sT[64+lane]*p1 : 0.f);
    val = wsum(val);
    if (lane == 0) out[b] = val*frcp(sum);
  }
}

extern "C" void kernel_launch(void* const* d_in, const int* in_sizes, int n_in,
                              void* d_out, int out_size, void* d_ws, size_t ws_size,
                              hipStream_t stream) {
  const float* X   = (const float*)d_in[0];
  const float* A   = (const float*)d_in[1];
  const float* M   = (const float*)d_in[2];
  const float* W1  = (const float*)d_in[3];
  const float* as1 = (const float*)d_in[4];
  const float* an1 = (const float*)d_in[5];
  const float* b1  = (const float*)d_in[6];
  const float* W2  = (const float*)d_in[7];
  const float* as2 = (const float*)d_in[8];
  const float* an2 = (const float*)d_in[9];
  const float* b2  = (const float*)d_in[10];
  const float* fc1 = (const float*)d_in[11];
  const float* fc2 = (const float*)d_in[12];
  float* out = (float*)d_out;

  // ws: Msig f32[12100] | W1tg f16[144*136] | W2tg f16[16*136] | fc2tg f16[112*136]
  float* Msig = (float*)d_ws;
  f16* W1tg  = (f16*)((char*)d_ws + 48400);
  f16* W2tg  = (f16*)((char*)d_ws + 48400 + W1ROWS*KP*2);
  f16* fc2tg = (f16*)((char*)d_ws + 48400 + W1ROWS*KP*2 + 16*KP*2);

  const int pre_items = NN + W1ROWS*KP + 16*KP + 112*KP;
  precomp_kernel<<<(pre_items + 255)/256, 256, 0, stream>>>(
      M, W1, as1, an1, W2, as2, an2, fc2, Msig, W1tg, W2tg, fc2tg);
  gat_fused<<<NB, T1, 0, stream>>>(X, A, Msig, W1tg, b1, W2tg,
                                   b2, fc1, fc2tg, out);
}